// Round 5
// baseline (1548.365 us; speedup 1.0000x reference)
//
#include <hip/hip_runtime.h>
#include <hip/hip_bf16.h>
#include <stdint.h>

#define N_LEVELS   16
#define LOG2_T     19
#define TABLE_SIZE (1u << LOG2_T)
#define PRIME_Y    2654435761u
#define PRIME_Z    805459861u

typedef float v2f __attribute__((ext_vector_type(2)));

// ============================ Kernel A: encode ============================
// One thread per point; low register footprint (target <=64 VGPR -> 8
// waves/SIMD for gather-latency hiding). Output transposed: a_ws[f][i],
// f in [0,32) planes of n floats -> every store is a coalesced full-line
// dword store; kernel B reads the same planes coalesced.
__global__ __launch_bounds__(256, 8)
void encode_kernel(const float* __restrict__ x,           // [N,3]
                   const float* __restrict__ tables,      // [16, T, 2]
                   const float* __restrict__ resolutions, // [16]
                   float* __restrict__ a_ws,              // [32, N]
                   int n)
{
    const int i  = blockIdx.x * blockDim.x + threadIdx.x;
    const int ip = (i < n) ? i : (n - 1);   // uniform CF; dup writes benign

    const float x0 = x[3 * ip + 0] * 0.5f + 0.5f;
    const float x1 = x[3 * ip + 1] * 0.5f + 0.5f;
    const float x2 = x[3 * ip + 2] * 0.5f + 0.5f;

    #pragma unroll
    for (int l = 0; l < N_LEVELS; ++l) {
        const float res = resolutions[l];
        const float px = x0 * res, py = x1 * res, pz = x2 * res;
        const float fx = floorf(px), fy = floorf(py), fz = floorf(pz);
        const float wx = px - fx, wy = py - fy, wz = pz - fz;
        const uint32_t cx = (uint32_t)fx;
        const uint32_t cy = (uint32_t)fy;
        const uint32_t cz = (uint32_t)fz;

        const uint32_t hx0 = cx,           hx1 = cx + 1u;
        const uint32_t hy0 = cy * PRIME_Y, hy1 = hy0 + PRIME_Y;
        const uint32_t hz0 = cz * PRIME_Z, hz1 = hz0 + PRIME_Z;

        const float wx0 = 1.0f - wx, wy0 = 1.0f - wy, wz0 = 1.0f - wz;

        const float* __restrict__ tab = tables + (size_t)l * (size_t)TABLE_SIZE * 2u;

        // issue all 8 gathers, then consume (compiler keeps 8 in flight)
        float2 fv[8];
        #pragma unroll
        for (int c = 0; c < 8; ++c) {
            const uint32_t h = ((c & 1) ? hx1 : hx0) ^
                               ((c & 2) ? hy1 : hy0) ^
                               ((c & 4) ? hz1 : hz0);
            const uint32_t idx = h & (TABLE_SIZE - 1u);
            fv[c] = *(const float2*)(tab + 2u * idx);
        }
        float f0 = 0.0f, f1 = 0.0f;
        #pragma unroll
        for (int c = 0; c < 8; ++c) {
            const float wgt = ((c & 1) ? wx : wx0) *
                              ((c & 2) ? wy : wy0) *
                              ((c & 4) ? wz : wz0);
            f0 = fmaf(wgt, fv[c].x, f0);
            f1 = fmaf(wgt, fv[c].y, f1);
        }
        a_ws[(size_t)(2 * l + 0) * n + ip] = f0;
        a_ws[(size_t)(2 * l + 1) * n + ip] = f1;
    }
}

// ============================ Kernel B: MLP ============================
// One thread per point. Weights scalarized (s_load + SGPR-operand FMA,
// proven in round 4 by VGPR=52/SGPR=96). v2f packing over output-channel
// pairs -> v_pk_fma_f32 halves FMA instruction count; k-order preserved.
__global__ __launch_bounds__(256, 3)
void mlp_kernel(const float* __restrict__ a_ws,   // [32, N]
                const float* __restrict__ W1,     // [32,64]
                const float* __restrict__ b1,     // [64]
                const float* __restrict__ W2,     // [64,64]
                const float* __restrict__ b2,     // [64]
                const float* __restrict__ W3,     // [64,1]
                const float* __restrict__ b3,     // [1]
                float* __restrict__ out,          // [N]
                int n)
{
    const int i  = blockIdx.x * blockDim.x + threadIdx.x;
    const int ip = (i < n) ? i : (n - 1);

    // coalesced plane reads: lane i reads plane[ip]
    float a[32];
    #pragma unroll
    for (int k = 0; k < 32; ++k)
        a[k] = a_ws[(size_t)k * n + ip];

    const v2f zero = {0.0f, 0.0f};

    // ---- layer 1: [32] @ [32,64] + b1, relu ----
    v2f H1[32];
    #pragma unroll
    for (int j2 = 0; j2 < 32; ++j2) {
        const float2 b = *(const float2*)&b1[2 * j2];
        H1[j2] = (v2f){b.x, b.y};
    }
    #pragma unroll
    for (int k = 0; k < 32; ++k) {
        const float ak = a[k];
        const v2f vA = {ak, ak};
        #pragma unroll
        for (int j4 = 0; j4 < 16; ++j4) {
            const float4 w = *(const float4*)&W1[k * 64 + j4 * 4];
            H1[j4 * 2 + 0] = __builtin_elementwise_fma(vA, (v2f){w.x, w.y}, H1[j4 * 2 + 0]);
            H1[j4 * 2 + 1] = __builtin_elementwise_fma(vA, (v2f){w.z, w.w}, H1[j4 * 2 + 1]);
        }
    }
    #pragma unroll
    for (int j2 = 0; j2 < 32; ++j2)
        H1[j2] = __builtin_elementwise_max(H1[j2], zero);

    // ---- layer 2 (two 32-wide halves) + layer 3 fused ----
    v2f acc = zero;
    #pragma unroll
    for (int half = 0; half < 2; ++half) {
        v2f H2[16];
        #pragma unroll
        for (int j2 = 0; j2 < 16; ++j2) {
            const float2 b = *(const float2*)&b2[half * 32 + 2 * j2];
            H2[j2] = (v2f){b.x, b.y};
        }
        #pragma unroll
        for (int k2 = 0; k2 < 32; ++k2) {
            const v2f hp = H1[k2];
            #pragma unroll
            for (int kk = 0; kk < 2; ++kk) {
                const float hk = kk ? hp.y : hp.x;
                const v2f vH = {hk, hk};
                const int k = 2 * k2 + kk;
                #pragma unroll
                for (int j4 = 0; j4 < 8; ++j4) {
                    const float4 w = *(const float4*)&W2[k * 64 + half * 32 + j4 * 4];
                    H2[j4 * 2 + 0] = __builtin_elementwise_fma(vH, (v2f){w.x, w.y}, H2[j4 * 2 + 0]);
                    H2[j4 * 2 + 1] = __builtin_elementwise_fma(vH, (v2f){w.z, w.w}, H2[j4 * 2 + 1]);
                }
            }
        }
        #pragma unroll
        for (int j2 = 0; j2 < 16; ++j2) {
            const float2 w3 = *(const float2*)&W3[half * 32 + 2 * j2];
            acc = __builtin_elementwise_fma(__builtin_elementwise_max(H2[j2], zero),
                                            (v2f){w3.x, w3.y}, acc);
        }
    }

    out[ip] = acc.x + acc.y + b3[0];
}

// ==================== Fallback: round-4 fused kernel ====================
__global__ __launch_bounds__(256, 4)
void hashgrid_mlp_fused(const float* __restrict__ x,
                        const float* __restrict__ tables,
                        const float* __restrict__ resolutions,
                        const float* __restrict__ W1,
                        const float* __restrict__ b1,
                        const float* __restrict__ W2,
                        const float* __restrict__ b2,
                        const float* __restrict__ W3,
                        const float* __restrict__ b3,
                        float* __restrict__ out,
                        int n)
{
    const int i  = blockIdx.x * blockDim.x + threadIdx.x;
    const int ip = (i < n) ? i : (n - 1);

    const float x0 = x[3 * ip + 0] * 0.5f + 0.5f;
    const float x1 = x[3 * ip + 1] * 0.5f + 0.5f;
    const float x2 = x[3 * ip + 2] * 0.5f + 0.5f;

    float h1[64];
    #pragma unroll
    for (int j = 0; j < 64; ++j) h1[j] = b1[j];

    #pragma unroll
    for (int l = 0; l < N_LEVELS; ++l) {
        const float res = resolutions[l];
        const float px = x0 * res, py = x1 * res, pz = x2 * res;
        const float fx = floorf(px), fy = floorf(py), fz = floorf(pz);
        const float wx = px - fx, wy = py - fy, wz = pz - fz;
        const uint32_t cx = (uint32_t)fx;
        const uint32_t cy = (uint32_t)fy;
        const uint32_t cz = (uint32_t)fz;
        const uint32_t hx0 = cx,           hx1 = cx + 1u;
        const uint32_t hy0 = cy * PRIME_Y, hy1 = hy0 + PRIME_Y;
        const uint32_t hz0 = cz * PRIME_Z, hz1 = hz0 + PRIME_Z;
        const float wx0 = 1.0f - wx, wy0 = 1.0f - wy, wz0 = 1.0f - wz;
        const float* __restrict__ tab = tables + (size_t)l * (size_t)TABLE_SIZE * 2u;

        float f0 = 0.0f, f1 = 0.0f;
        #pragma unroll
        for (int c = 0; c < 8; ++c) {
            const uint32_t h = ((c & 1) ? hx1 : hx0) ^
                               ((c & 2) ? hy1 : hy0) ^
                               ((c & 4) ? hz1 : hz0);
            const uint32_t idx = h & (TABLE_SIZE - 1u);
            const float2 fv = *(const float2*)(tab + 2u * idx);
            const float wgt = ((c & 1) ? wx : wx0) *
                              ((c & 2) ? wy : wy0) *
                              ((c & 4) ? wz : wz0);
            f0 = fmaf(wgt, fv.x, f0);
            f1 = fmaf(wgt, fv.y, f1);
        }
        const float* __restrict__ w1a = W1 + (2 * l + 0) * 64;
        const float* __restrict__ w1b = W1 + (2 * l + 1) * 64;
        #pragma unroll
        for (int j = 0; j < 64; ++j)
            h1[j] = fmaf(f1, w1b[j], fmaf(f0, w1a[j], h1[j]));
    }

    #pragma unroll
    for (int j = 0; j < 64; ++j) h1[j] = fmaxf(h1[j], 0.0f);

    float accum = b3[0];
    #pragma unroll
    for (int half = 0; half < 2; ++half) {
        float h2[32];
        #pragma unroll
        for (int j = 0; j < 32; ++j) h2[j] = b2[half * 32 + j];
        #pragma unroll
        for (int k = 0; k < 64; ++k) {
            const float hk = h1[k];
            const float* __restrict__ w2row = W2 + k * 64 + half * 32;
            #pragma unroll
            for (int j = 0; j < 32; ++j)
                h2[j] = fmaf(hk, w2row[j], h2[j]);
        }
        #pragma unroll
        for (int j = 0; j < 32; ++j)
            accum = fmaf(fmaxf(h2[j], 0.0f), W3[half * 32 + j], accum);
    }
    out[ip] = accum;
}

extern "C" void kernel_launch(void* const* d_in, const int* in_sizes, int n_in,
                              void* d_out, int out_size, void* d_ws, size_t ws_size,
                              hipStream_t stream) {
    const float* x           = (const float*)d_in[0];
    const float* tables      = (const float*)d_in[1];
    const float* resolutions = (const float*)d_in[2];
    const float* W1          = (const float*)d_in[3];
    const float* b1          = (const float*)d_in[4];
    const float* W2          = (const float*)d_in[5];
    const float* b2          = (const float*)d_in[6];
    const float* W3          = (const float*)d_in[7];
    const float* b3          = (const float*)d_in[8];
    float* out               = (float*)d_out;

    const int n = out_size;  // 2,000,000
    const int block = 256;
    const int grid = (n + block - 1) / block;
    const size_t ws_needed = (size_t)n * 32u * sizeof(float);

    if (ws_size >= ws_needed) {
        float* a_ws = (float*)d_ws;
        encode_kernel<<<grid, block, 0, stream>>>(x, tables, resolutions, a_ws, n);
        mlp_kernel<<<grid, block, 0, stream>>>(a_ws, W1, b1, W2, b2, W3, b3, out, n);
    } else {
        hashgrid_mlp_fused<<<grid, block, 0, stream>>>(
            x, tables, resolutions, W1, b1, W2, b2, W3, b3, out, n);
    }
}